// Round 1
// baseline (525.285 us; speedup 1.0000x reference)
//
#include <hip/hip_runtime.h>
#include <hip/hip_bf16.h>
#include <cstdint>

#define DEV static __device__ __forceinline__

typedef __attribute__((ext_vector_type(8))) short short8_;
typedef __attribute__((ext_vector_type(4))) float float4_;
typedef __attribute__((ext_vector_type(4))) float f4v;
typedef __attribute__((ext_vector_type(4))) unsigned short u16x4;
typedef unsigned short u16;

constexpr int Bb   = 2;
constexpr int Ls   = 2048;
constexpr int DIMc = 1024;
constexpr int Hh   = 16;
constexpr int Dd   = 64;
constexpr int BL   = Bb * Ls;   // 4096
constexpr int HD   = Hh * Dd;   // 1024

DEV u16 f2bf(float f) {
  union { float f; uint32_t u; } v; v.f = f;
  return (u16)((v.u + 0x7fffu + ((v.u >> 16) & 1u)) >> 16);
}

DEV float4_ mfma16(short8_ a, short8_ b, float4_ c) {
  return __builtin_amdgcn_mfma_f32_16x16x32_bf16(a, b, c, 0, 0, 0);
}

DEV void gload_lds16(const void* g, void* l) {
  __builtin_amdgcn_global_load_lds(
      (const __attribute__((address_space(1))) void*)g,
      (__attribute__((address_space(3))) void*)l, 16, 0, 0);
}

// ---------------- cast fp32 -> bf16 (vectorized) ----------------
__global__ void k_cast(const float* __restrict__ src, u16* __restrict__ dst, int n4) {
  int i = blockIdx.x * 256 + threadIdx.x;
  if (i >= n4) return;
  f4v v = ((const f4v*)src)[i];
  u16x4 o = { f2bf(v[0]), f2bf(v[1]), f2bf(v[2]), f2bf(v[3]) };
  ((u16x4*)dst)[i] = o;
}

// ---------------- transpose + cast W [K=1024][N=1024] -> WT bf16 [N][K] ----------------
__global__ void k_trans(const float* __restrict__ W, u16* __restrict__ WT) {
  __shared__ float t[64][65];
  int tx = threadIdx.x & 63;
  int tg = threadIdx.x >> 6;
  int n0 = blockIdx.x * 64;
  int k0 = blockIdx.y * 64;
#pragma unroll
  for (int i = 0; i < 16; ++i) {
    int r = tg * 16 + i;
    t[r][tx] = W[(size_t)(k0 + r) * HD + n0 + tx];
  }
  __syncthreads();
#pragma unroll
  for (int i = 0; i < 16; ++i) {
    int r = tg * 16 + i;
    WT[(size_t)(n0 + r) * DIMc + k0 + tx] = f2bf(t[tx][r]);
  }
}

// ---------------- gate score dot products (fp32) ----------------
__global__ void k_gates(const float* __restrict__ keys, const float* __restrict__ Wt,
                        const float* __restrict__ bt, const float* __restrict__ Wi,
                        const float* __restrict__ bi, const float* __restrict__ focus,
                        float* __restrict__ ts, float* __restrict__ is_, float* __restrict__ rs) {
  int wv = threadIdx.x >> 6, ln = threadIdx.x & 63;
  int row = blockIdx.x * 4 + wv;          // 0..4095
  int b = row >> 11;
  const float* kr = keys + (size_t)row * DIMc;
  const float* fr = focus + (size_t)b * DIMc;
  float st = 0.f, si = 0.f, sr = 0.f;
  for (int j = ln; j < DIMc; j += 64) {
    float kv = kr[j];
    st += kv * Wt[j]; si += kv * Wi[j]; sr += kv * fr[j];
  }
#pragma unroll
  for (int m = 1; m < 64; m <<= 1) {
    st += __shfl_xor(st, m); si += __shfl_xor(si, m); sr += __shfl_xor(sr, m);
  }
  if (ln == 0) { ts[row] = st + bt[0]; is_[row] = si + bi[0]; rs[row] = sr; }
}

// ---------------- gate softmaxes + combined (fp32, max-subtracted) ----------------
__global__ void k_combined(const float* __restrict__ ts, const float* __restrict__ is_,
                           const float* __restrict__ rs, const float* __restrict__ tw,
                           const float* __restrict__ iw, float* __restrict__ comb) {
  int b = blockIdx.x, t = threadIdx.x;
  __shared__ float red[3][4];
  float lt[8], li[8], lr[8];
  float m3[3] = {-1e30f, -1e30f, -1e30f};
#pragma unroll
  for (int i = 0; i < 8; ++i) {
    int gi = b * Ls + i * 256 + t;
    lt[i] = ts[gi] * tw[gi];
    li[i] = is_[gi] * iw[gi];
    lr[i] = rs[gi];
    m3[0] = fmaxf(m3[0], lt[i]); m3[1] = fmaxf(m3[1], li[i]); m3[2] = fmaxf(m3[2], lr[i]);
  }
#pragma unroll
  for (int q = 0; q < 3; ++q) {
    float v = m3[q];
#pragma unroll
    for (int m = 32; m; m >>= 1) v = fmaxf(v, __shfl_xor(v, m));
    if ((t & 63) == 0) red[q][t >> 6] = v;
  }
  __syncthreads();
#pragma unroll
  for (int q = 0; q < 3; ++q)
    m3[q] = fmaxf(fmaxf(red[q][0], red[q][1]), fmaxf(red[q][2], red[q][3]));
  __syncthreads();
  float s3[3] = {0.f, 0.f, 0.f};
#pragma unroll
  for (int i = 0; i < 8; ++i) {
    lt[i] = __expf(lt[i] - m3[0]); s3[0] += lt[i];
    li[i] = __expf(li[i] - m3[1]); s3[1] += li[i];
    lr[i] = __expf(lr[i] - m3[2]); s3[2] += lr[i];
  }
#pragma unroll
  for (int q = 0; q < 3; ++q) {
    float v = s3[q];
#pragma unroll
    for (int m = 32; m; m >>= 1) v += __shfl_xor(v, m);
    if ((t & 63) == 0) red[q][t >> 6] = v;
  }
  __syncthreads();
#pragma unroll
  for (int q = 0; q < 3; ++q) s3[q] = red[q][0] + red[q][1] + red[q][2] + red[q][3];
  float rt = 1.f / s3[0], ri = 1.f / s3[1], rr = 1.f / s3[2];
  const float third = 1.f / 3.f;
#pragma unroll
  for (int i = 0; i < 8; ++i) {
    int gi = b * Ls + i * 256 + t;
    comb[gi] = (lt[i] * rt + li[i] * ri + lr[i] * rr) * third;
  }
}

// ---------------- GEMM: C[M=4096][N=1024] = A[4096][1024] @ BT[N][K]^T + bias ----------------
// MODE 0: out bf16 [B,H,L,D]   MODE 2: out bf16 vT [B,H,D,L]   MODE 3: out fp32 [M][N]
template <int MODE>
__launch_bounds__(256, 2)
__global__ void k_gemm(const u16* __restrict__ A, const u16* __restrict__ BT,
                       const float* __restrict__ bias, void* __restrict__ out) {
  __shared__ __align__(16) u16 As[128 * 32];
  __shared__ __align__(16) u16 Bs[128 * 32];
  const int tid = threadIdx.x, wv = tid >> 6, ln = tid & 63;
  const int g = ln >> 4, c = ln & 15;
  const int m0 = blockIdx.x * 128, n0 = blockIdx.y * 128;
  const int wm = wv >> 1, wn = wv & 1;
  const float4_ z4 = {0.f, 0.f, 0.f, 0.f};
  float4_ acc[4][4];
#pragma unroll
  for (int i = 0; i < 4; ++i)
#pragma unroll
    for (int j = 0; j < 4; ++j) acc[i][j] = z4;
  const int lrow = ln >> 2, lcol = (ln & 3) * 8;
  for (int k0 = 0; k0 < 1024; k0 += 32) {
#pragma unroll
    for (int s = 0; s < 2; ++s) {
      int r0 = wv * 32 + s * 16;
      gload_lds16(A  + (size_t)(m0 + r0 + lrow) * 1024 + k0 + lcol, &As[r0 * 32]);
      gload_lds16(BT + (size_t)(n0 + r0 + lrow) * 1024 + k0 + lcol, &Bs[r0 * 32]);
    }
    __syncthreads();
    short8_ af[4], bfr[4];
#pragma unroll
    for (int mt = 0; mt < 4; ++mt)
      af[mt] = *(const short8_*)&As[(wm * 64 + mt * 16 + c) * 32 + g * 8];
#pragma unroll
    for (int nt = 0; nt < 4; ++nt)
      bfr[nt] = *(const short8_*)&Bs[(wn * 64 + nt * 16 + c) * 32 + g * 8];
#pragma unroll
    for (int mt = 0; mt < 4; ++mt)
#pragma unroll
      for (int nt = 0; nt < 4; ++nt)
        acc[mt][nt] = mfma16(af[mt], bfr[nt], acc[mt][nt]);
    __syncthreads();
  }
  // epilogue: C row = m0+wm*64+mt*16+g*4+r ; col = n0+wn*64+nt*16+c
  if constexpr (MODE == 3) {
    float* O = (float*)out;
#pragma unroll
    for (int mt = 0; mt < 4; ++mt)
#pragma unroll
      for (int nt = 0; nt < 4; ++nt) {
        int n = n0 + wn * 64 + nt * 16 + c;
        float bv = bias[n];
#pragma unroll
        for (int r = 0; r < 4; ++r) {
          int m = m0 + wm * 64 + mt * 16 + g * 4 + r;
          O[(size_t)m * HD + n] = acc[mt][nt][r] + bv;
        }
      }
  } else if constexpr (MODE == 2) {
    u16* vT = (u16*)out;
#pragma unroll
    for (int mt = 0; mt < 4; ++mt)
#pragma unroll
      for (int nt = 0; nt < 4; ++nt) {
        int n = n0 + wn * 64 + nt * 16 + c;
        float bv = bias[n];
        int h = n >> 6, d = n & 63;
        int mrow = m0 + wm * 64 + mt * 16 + g * 4;
        int b = mrow >> 11, l = mrow & 2047;
        u16x4 o = { f2bf(acc[mt][nt][0] + bv), f2bf(acc[mt][nt][1] + bv),
                    f2bf(acc[mt][nt][2] + bv), f2bf(acc[mt][nt][3] + bv) };
        *(u16x4*)&vT[((size_t)((b * Hh + h) * Dd + d)) * Ls + l] = o;
      }
  } else {
    u16* Q = (u16*)out;
#pragma unroll
    for (int mt = 0; mt < 4; ++mt)
#pragma unroll
      for (int nt = 0; nt < 4; ++nt) {
        int n = n0 + wn * 64 + nt * 16 + c;
        float bv = bias[n];
        int h = n >> 6, d = n & 63;
#pragma unroll
        for (int r = 0; r < 4; ++r) {
          int m = m0 + wm * 64 + mt * 16 + g * 4 + r;
          int b = m >> 11, l = m & 2047;
          Q[((size_t)((b * Hh + h) * Ls + l)) * Dd + d] = f2bf(acc[mt][nt][r] + bv);
        }
      }
  }
}

// ---------------- attention: 1 WG per (b,h,16 q-rows); 4 waves x 512 keys ----------------
__launch_bounds__(256, 2)
__global__ void k_attn(const u16* __restrict__ q_bh, const u16* __restrict__ k_bh,
                       const u16* __restrict__ vT, const float* __restrict__ comb_g,
                       float* __restrict__ wout, u16* __restrict__ ctx) {
  __shared__ float comb[Ls];
  __shared__ __align__(16) u16 e_lds[4][16][32];
  __shared__ float sums_p[4][16];
  __shared__ float inv_s[16];
  __shared__ float out_p[4][16][64];
  const int bid = blockIdx.x;
  const int bh = bid >> 7, rb = bid & 127;
  const int b = bh >> 4, h = bh & 15;
  const int l0 = rb * 16;
  const int wv = threadIdx.x >> 6, ln = threadIdx.x & 63;
  const int g = ln >> 4, c = ln & 15;
  for (int i = threadIdx.x; i < Ls; i += 256) comb[i] = comb_g[b * Ls + i] * 0.125f;
  const u16* qb = q_bh + ((size_t)bh * Ls + l0) * Dd;
  short8_ aq0 = *(const short8_*)&qb[c * Dd + g * 8];
  short8_ aq1 = *(const short8_*)&qb[c * Dd + 32 + g * 8];
  const u16* kb = k_bh + (size_t)bh * Ls * Dd;
  const u16* vb = vT + (size_t)bh * Dd * Ls;
  const int key0 = wv * 512;
  const float4_ z4 = {0.f, 0.f, 0.f, 0.f};
  float4_ accO[4];
#pragma unroll
  for (int dt = 0; dt < 4; ++dt) accO[dt] = z4;
  float rsum[4] = {0.f, 0.f, 0.f, 0.f};
  __syncthreads();
  // ---- pass 1: rowsums + unnormalized PV ----
  for (int kt2 = 0; kt2 < 16; ++kt2) {
    int kbase = key0 + kt2 * 32;
#pragma unroll
    for (int p = 0; p < 2; ++p) {
      int ky = kbase + p * 16;
      short8_ bk0 = *(const short8_*)&kb[(size_t)(ky + c) * Dd + g * 8];
      short8_ bk1 = *(const short8_*)&kb[(size_t)(ky + c) * Dd + 32 + g * 8];
      float4_ s = mfma16(aq0, bk0, z4);
      s = mfma16(aq1, bk1, s);
      float cc = comb[ky + c];
#pragma unroll
      for (int r = 0; r < 4; ++r) {
        float e = __expf(s[r] * cc);
        rsum[r] += e;
        e_lds[wv][g * 4 + r][p * 16 + c] = f2bf(e);
      }
    }
    short8_ ea = *(const short8_*)&e_lds[wv][c][g * 8];
#pragma unroll
    for (int dt = 0; dt < 4; ++dt) {
      short8_ bv = *(const short8_*)&vb[(size_t)(dt * 16 + c) * Ls + kbase + g * 8];
      accO[dt] = mfma16(ea, bv, accO[dt]);
    }
  }
  // reduce rowsums across 16 lanes of each group, then across waves
#pragma unroll
  for (int m = 1; m < 16; m <<= 1)
#pragma unroll
    for (int r = 0; r < 4; ++r) rsum[r] += __shfl_xor(rsum[r], m);
  if (c == 0)
#pragma unroll
    for (int r = 0; r < 4; ++r) sums_p[wv][g * 4 + r] = rsum[r];
#pragma unroll
  for (int dt = 0; dt < 4; ++dt)
#pragma unroll
    for (int r = 0; r < 4; ++r) out_p[wv][g * 4 + r][dt * 16 + c] = accO[dt][r];
  __syncthreads();
  if (threadIdx.x < 16) {
    float s = sums_p[0][threadIdx.x] + sums_p[1][threadIdx.x] +
              sums_p[2][threadIdx.x] + sums_p[3][threadIdx.x];
    inv_s[threadIdx.x] = 1.0f / s;
  }
  __syncthreads();
  {
    int row = threadIdx.x >> 4, c0 = (threadIdx.x & 15) * 4;
    float iv = inv_s[row];
    float vx = 0.f, vy = 0.f, vz = 0.f, vw = 0.f;
#pragma unroll
    for (int w = 0; w < 4; ++w) {
      const float* p = &out_p[w][row][c0];
      vx += p[0]; vy += p[1]; vz += p[2]; vw += p[3];
    }
    u16x4 o = { f2bf(vx * iv), f2bf(vy * iv), f2bf(vz * iv), f2bf(vw * iv) };
    *(u16x4*)&ctx[((size_t)b * Ls + l0 + row) * HD + h * Dd + c0] = o;
  }
  // ---- pass 2: recompute + write normalized weights ----
  float ivr[4];
#pragma unroll
  for (int r = 0; r < 4; ++r) ivr[r] = inv_s[g * 4 + r];
  float* wb = wout + ((size_t)bh * Ls + l0) * Ls;
  for (int kt = 0; kt < 32; ++kt) {
    int ky = key0 + kt * 16;
    short8_ bk0 = *(const short8_*)&kb[(size_t)(ky + c) * Dd + g * 8];
    short8_ bk1 = *(const short8_*)&kb[(size_t)(ky + c) * Dd + 32 + g * 8];
    float4_ s = mfma16(aq0, bk0, z4);
    s = mfma16(aq1, bk1, s);
    float cc = comb[ky + c];
#pragma unroll
    for (int r = 0; r < 4; ++r)
      wb[(size_t)(g * 4 + r) * Ls + ky + c] = __expf(s[r] * cc) * ivr[r];
  }
}

// ---------------- launch ----------------
extern "C" void kernel_launch(void* const* d_in, const int* in_sizes, int n_in,
                              void* d_out, int out_size, void* d_ws, size_t ws_size,
                              hipStream_t stream) {
  (void)in_sizes; (void)n_in; (void)out_size; (void)ws_size;
  const float* query = (const float*)d_in[0];
  const float* keys  = (const float*)d_in[1];
  const float* values= (const float*)d_in[2];
  const float* focus = (const float*)d_in[3];
  const float* twg   = (const float*)d_in[4];
  const float* iwg   = (const float*)d_in[5];
  const float* Wq = (const float*)d_in[6];  const float* bq = (const float*)d_in[7];
  const float* Wk = (const float*)d_in[8];  const float* bk = (const float*)d_in[9];
  const float* Wv = (const float*)d_in[10]; const float* bv = (const float*)d_in[11];
  const float* Wp = (const float*)d_in[12]; const float* bp = (const float*)d_in[13];
  const float* Wt = (const float*)d_in[14]; const float* bt = (const float*)d_in[15];
  const float* Wi = (const float*)d_in[16]; const float* bi = (const float*)d_in[17];

  char* ws = (char*)d_ws;
  size_t off = 0;
  auto alloc = [&](size_t bytes) -> char* {
    char* p = ws + off; off += (bytes + 255) & ~(size_t)255; return p;
  };
  const size_t NTOK = (size_t)BL * DIMc;          // 4,194,304
  u16* qx   = (u16*)alloc(NTOK * 2);
  u16* kx   = (u16*)alloc(NTOK * 2);
  u16* vx   = (u16*)alloc(NTOK * 2);
  u16* WqT  = (u16*)alloc((size_t)DIMc * HD * 2);
  u16* WkT  = (u16*)alloc((size_t)DIMc * HD * 2);
  u16* WvT  = (u16*)alloc((size_t)DIMc * HD * 2);
  u16* WpT  = (u16*)alloc((size_t)DIMc * HD * 2);
  u16* q_bh = (u16*)alloc(NTOK * 2);
  u16* k_bh = (u16*)alloc(NTOK * 2);
  u16* vTb  = (u16*)alloc(NTOK * 2);
  u16* ctx  = (u16*)alloc(NTOK * 2);
  float* ts   = (float*)alloc((size_t)BL * 4);
  float* is_  = (float*)alloc((size_t)BL * 4);
  float* rs   = (float*)alloc((size_t)BL * 4);
  float* comb = (float*)alloc((size_t)BL * 4);

  float* out_f = (float*)d_out;
  float* w_out = out_f + (size_t)BL * HD;   // weights region

  const int n4 = (int)(NTOK / 4);
  k_cast<<<4096, 256, 0, stream>>>(query,  qx, n4);
  k_cast<<<4096, 256, 0, stream>>>(keys,   kx, n4);
  k_cast<<<4096, 256, 0, stream>>>(values, vx, n4);
  dim3 tg(16, 16);
  k_trans<<<tg, 256, 0, stream>>>(Wq, WqT);
  k_trans<<<tg, 256, 0, stream>>>(Wk, WkT);
  k_trans<<<tg, 256, 0, stream>>>(Wv, WvT);
  k_trans<<<tg, 256, 0, stream>>>(Wp, WpT);
  k_gates<<<1024, 256, 0, stream>>>(keys, Wt, bt, Wi, bi, focus, ts, is_, rs);
  k_combined<<<2, 256, 0, stream>>>(ts, is_, rs, twg, iwg, comb);
  dim3 gg(32, 8);
  k_gemm<0><<<gg, 256, 0, stream>>>(qx, WqT, bq, q_bh);
  k_gemm<0><<<gg, 256, 0, stream>>>(kx, WkT, bk, k_bh);
  k_gemm<2><<<gg, 256, 0, stream>>>(vx, WvT, bv, vTb);
  k_attn<<<4096, 256, 0, stream>>>(q_bh, k_bh, vTb, comb, w_out, ctx);
  k_gemm<3><<<gg, 256, 0, stream>>>(ctx, WpT, bp, out_f);
}

// Round 2
// 341.452 us; speedup vs baseline: 1.5384x; 1.5384x over previous
//
#include <hip/hip_runtime.h>
#include <hip/hip_bf16.h>
#include <cstdint>

#define DEV static __device__ __forceinline__

typedef __attribute__((ext_vector_type(8))) short short8_;
typedef __attribute__((ext_vector_type(4))) float float4_;
typedef __attribute__((ext_vector_type(4))) float f4v;
typedef __attribute__((ext_vector_type(4))) unsigned short u16x4;
typedef unsigned short u16;

constexpr int Bb   = 2;
constexpr int Ls   = 2048;
constexpr int DIMc = 1024;
constexpr int Hh   = 16;
constexpr int Dd   = 64;
constexpr int BL   = Bb * Ls;   // 4096
constexpr int HD   = Hh * Dd;   // 1024

DEV u16 f2bf(float f) {
  union { float f; uint32_t u; } v; v.f = f;
  return (u16)((v.u + 0x7fffu + ((v.u >> 16) & 1u)) >> 16);
}

DEV float4_ mfma16(short8_ a, short8_ b, float4_ c) {
  return __builtin_amdgcn_mfma_f32_16x16x32_bf16(a, b, c, 0, 0, 0);
}

DEV void gload_lds16(const void* g, void* l) {
  __builtin_amdgcn_global_load_lds(
      (const __attribute__((address_space(1))) void*)g,
      (__attribute__((address_space(3))) void*)l, 16, 0, 0);
}

// ---------------- cast fp32 -> bf16 (vectorized) ----------------
__global__ void k_cast(const float* __restrict__ src, u16* __restrict__ dst, int n4) {
  int i = blockIdx.x * 256 + threadIdx.x;
  if (i >= n4) return;
  f4v v = ((const f4v*)src)[i];
  u16x4 o = { f2bf(v[0]), f2bf(v[1]), f2bf(v[2]), f2bf(v[3]) };
  ((u16x4*)dst)[i] = o;
}

// ---------------- transpose + cast W [K=1024][N=1024] -> WT bf16 [N][K] ----------------
__global__ void k_trans(const float* __restrict__ W, u16* __restrict__ WT) {
  __shared__ float t[64][65];
  int tx = threadIdx.x & 63;
  int tg = threadIdx.x >> 6;
  int n0 = blockIdx.x * 64;
  int k0 = blockIdx.y * 64;
#pragma unroll
  for (int i = 0; i < 16; ++i) {
    int r = tg * 16 + i;
    t[r][tx] = W[(size_t)(k0 + r) * HD + n0 + tx];
  }
  __syncthreads();
#pragma unroll
  for (int i = 0; i < 16; ++i) {
    int r = tg * 16 + i;
    WT[(size_t)(n0 + r) * DIMc + k0 + tx] = f2bf(t[tx][r]);
  }
}

// ---------------- gate score dot products (fp32) ----------------
__global__ void k_gates(const float* __restrict__ keys, const float* __restrict__ Wt,
                        const float* __restrict__ bt, const float* __restrict__ Wi,
                        const float* __restrict__ bi, const float* __restrict__ focus,
                        float* __restrict__ ts, float* __restrict__ is_, float* __restrict__ rs) {
  int wv = threadIdx.x >> 6, ln = threadIdx.x & 63;
  int row = blockIdx.x * 4 + wv;          // 0..4095
  int b = row >> 11;
  const float* kr = keys + (size_t)row * DIMc;
  const float* fr = focus + (size_t)b * DIMc;
  float st = 0.f, si = 0.f, sr = 0.f;
  for (int j = ln; j < DIMc; j += 64) {
    float kv = kr[j];
    st += kv * Wt[j]; si += kv * Wi[j]; sr += kv * fr[j];
  }
#pragma unroll
  for (int m = 1; m < 64; m <<= 1) {
    st += __shfl_xor(st, m); si += __shfl_xor(si, m); sr += __shfl_xor(sr, m);
  }
  if (ln == 0) { ts[row] = st + bt[0]; is_[row] = si + bi[0]; rs[row] = sr; }
}

// ---------------- gate softmaxes + combined (fp32, max-subtracted) ----------------
__global__ void k_combined(const float* __restrict__ ts, const float* __restrict__ is_,
                           const float* __restrict__ rs, const float* __restrict__ tw,
                           const float* __restrict__ iw, float* __restrict__ comb) {
  int b = blockIdx.x, t = threadIdx.x;
  __shared__ float red[3][4];
  float lt[8], li[8], lr[8];
  float m3[3] = {-1e30f, -1e30f, -1e30f};
#pragma unroll
  for (int i = 0; i < 8; ++i) {
    int gi = b * Ls + i * 256 + t;
    lt[i] = ts[gi] * tw[gi];
    li[i] = is_[gi] * iw[gi];
    lr[i] = rs[gi];
    m3[0] = fmaxf(m3[0], lt[i]); m3[1] = fmaxf(m3[1], li[i]); m3[2] = fmaxf(m3[2], lr[i]);
  }
#pragma unroll
  for (int q = 0; q < 3; ++q) {
    float v = m3[q];
#pragma unroll
    for (int m = 32; m; m >>= 1) v = fmaxf(v, __shfl_xor(v, m));
    if ((t & 63) == 0) red[q][t >> 6] = v;
  }
  __syncthreads();
#pragma unroll
  for (int q = 0; q < 3; ++q)
    m3[q] = fmaxf(fmaxf(red[q][0], red[q][1]), fmaxf(red[q][2], red[q][3]));
  __syncthreads();
  float s3[3] = {0.f, 0.f, 0.f};
#pragma unroll
  for (int i = 0; i < 8; ++i) {
    lt[i] = __expf(lt[i] - m3[0]); s3[0] += lt[i];
    li[i] = __expf(li[i] - m3[1]); s3[1] += li[i];
    lr[i] = __expf(lr[i] - m3[2]); s3[2] += lr[i];
  }
#pragma unroll
  for (int q = 0; q < 3; ++q) {
    float v = s3[q];
#pragma unroll
    for (int m = 32; m; m >>= 1) v += __shfl_xor(v, m);
    if ((t & 63) == 0) red[q][t >> 6] = v;
  }
  __syncthreads();
#pragma unroll
  for (int q = 0; q < 3; ++q) s3[q] = red[q][0] + red[q][1] + red[q][2] + red[q][3];
  float rt = 1.f / s3[0], ri = 1.f / s3[1], rr = 1.f / s3[2];
  const float third = 1.f / 3.f;
#pragma unroll
  for (int i = 0; i < 8; ++i) {
    int gi = b * Ls + i * 256 + t;
    comb[gi] = (lt[i] * rt + li[i] * ri + lr[i] * rr) * third;
  }
}

// ---------------- GEMM: C[M=4096][N=1024] = A[4096][1024] @ BT[N][K]^T + bias ----------------
// MODE 0: out bf16 [B,H,L,D]   MODE 2: out bf16 vT [B,H,D,L]   MODE 3: out fp32 [M][N]
template <int MODE>
__launch_bounds__(256, 2)
__global__ void k_gemm(const u16* __restrict__ A, const u16* __restrict__ BT,
                       const float* __restrict__ bias, void* __restrict__ out) {
  __shared__ __align__(16) u16 As[128 * 32];
  __shared__ __align__(16) u16 Bs[128 * 32];
  const int tid = threadIdx.x, wv = tid >> 6, ln = tid & 63;
  const int g = ln >> 4, c = ln & 15;
  const int m0 = blockIdx.x * 128, n0 = blockIdx.y * 128;
  const int wm = wv >> 1, wn = wv & 1;
  const float4_ z4 = {0.f, 0.f, 0.f, 0.f};
  float4_ acc[4][4];
#pragma unroll
  for (int i = 0; i < 4; ++i)
#pragma unroll
    for (int j = 0; j < 4; ++j) acc[i][j] = z4;
  const int lrow = ln >> 2, lcol = (ln & 3) * 8;
  for (int k0 = 0; k0 < 1024; k0 += 32) {
#pragma unroll
    for (int s = 0; s < 2; ++s) {
      int r0 = wv * 32 + s * 16;
      gload_lds16(A  + (size_t)(m0 + r0 + lrow) * 1024 + k0 + lcol, &As[r0 * 32]);
      gload_lds16(BT + (size_t)(n0 + r0 + lrow) * 1024 + k0 + lcol, &Bs[r0 * 32]);
    }
    __syncthreads();
    short8_ af[4], bfr[4];
#pragma unroll
    for (int mt = 0; mt < 4; ++mt)
      af[mt] = *(const short8_*)&As[(wm * 64 + mt * 16 + c) * 32 + g * 8];
#pragma unroll
    for (int nt = 0; nt < 4; ++nt)
      bfr[nt] = *(const short8_*)&Bs[(wn * 64 + nt * 16 + c) * 32 + g * 8];
#pragma unroll
    for (int mt = 0; mt < 4; ++mt)
#pragma unroll
      for (int nt = 0; nt < 4; ++nt)
        acc[mt][nt] = mfma16(af[mt], bfr[nt], acc[mt][nt]);
    __syncthreads();
  }
  // epilogue: C row = m0+wm*64+mt*16+g*4+r ; col = n0+wn*64+nt*16+c
  if constexpr (MODE == 3) {
    float* O = (float*)out;
#pragma unroll
    for (int mt = 0; mt < 4; ++mt)
#pragma unroll
      for (int nt = 0; nt < 4; ++nt) {
        int n = n0 + wn * 64 + nt * 16 + c;
        float bv = bias[n];
#pragma unroll
        for (int r = 0; r < 4; ++r) {
          int m = m0 + wm * 64 + mt * 16 + g * 4 + r;
          O[(size_t)m * HD + n] = acc[mt][nt][r] + bv;
        }
      }
  } else if constexpr (MODE == 2) {
    u16* vT = (u16*)out;
#pragma unroll
    for (int mt = 0; mt < 4; ++mt)
#pragma unroll
      for (int nt = 0; nt < 4; ++nt) {
        int n = n0 + wn * 64 + nt * 16 + c;
        float bv = bias[n];
        int h = n >> 6, d = n & 63;
        int mrow = m0 + wm * 64 + mt * 16 + g * 4;
        int b = mrow >> 11, l = mrow & 2047;
        u16x4 o = { f2bf(acc[mt][nt][0] + bv), f2bf(acc[mt][nt][1] + bv),
                    f2bf(acc[mt][nt][2] + bv), f2bf(acc[mt][nt][3] + bv) };
        *(u16x4*)&vT[((size_t)((b * Hh + h) * Dd + d)) * Ls + l] = o;
      }
  } else {
    u16* Q = (u16*)out;
#pragma unroll
    for (int mt = 0; mt < 4; ++mt)
#pragma unroll
      for (int nt = 0; nt < 4; ++nt) {
        int n = n0 + wn * 64 + nt * 16 + c;
        float bv = bias[n];
        int h = n >> 6, d = n & 63;
#pragma unroll
        for (int r = 0; r < 4; ++r) {
          int m = m0 + wm * 64 + mt * 16 + g * 4 + r;
          int b = m >> 11, l = m & 2047;
          Q[((size_t)((b * Hh + h) * Ls + l)) * Dd + d] = f2bf(acc[mt][nt][r] + bv);
        }
      }
  }
}

// ---------------- attention v2 ----------------
// 1024 WGs (XCD-swizzled), 4 waves each. WG = (bh, 64 q-rows); wave w owns rows
// l0+w*16..+15 across ALL 2048 keys. K/V^T double-buffered in LDS via
// global_load_lds (source pre-swizzled, reads XOR-swizzled -> conflict-free).
// Pass 1: rowsums + PV (normalized ctx). Pass 2: recompute S^T, float4 weight stores.
__launch_bounds__(256, 3)
__global__ void k_attn2(const u16* __restrict__ q_bh, const u16* __restrict__ k_bh,
                        const u16* __restrict__ vT, const float* __restrict__ comb_g,
                        float* __restrict__ wout, u16* __restrict__ ctx) {
  __shared__ __align__(16) u16 Kt[2][64][64];
  __shared__ __align__(16) u16 Vt[2][64][64];   // aliased as out_lds after pass 1
  __shared__ float comb[Ls];
  __shared__ __align__(16) u16 e_w[4][16][72];
  __shared__ float inv_w[4][16];

  const int bid = blockIdx.x;
  const int logical = (bid & 7) * 128 + (bid >> 3);   // bijective: 4 bh per XCD
  const int bh = logical >> 5, qb = logical & 31;
  const int b = bh >> 4, h = bh & 15;
  const int l0 = qb * 64;
  const int w = threadIdx.x >> 6, ln = threadIdx.x & 63;
  const int g = ln >> 4, c = ln & 15;
  const int srow = ln >> 3, x8 = ln & 7;   // staging lane coords
  const float4_ z4 = {0.f, 0.f, 0.f, 0.f};

  const u16* kbh = k_bh + (size_t)bh * Ls * Dd;
  const u16* vbh = vT + (size_t)bh * Dd * Ls;

  // per-wave Q fragments (rows l0 + w*16 + c)
  const u16* qp = q_bh + ((size_t)bh * Ls + l0 + w * 16) * Dd;
  short8_ aq0 = *(const short8_*)&qp[c * Dd + g * 8];
  short8_ aq1 = *(const short8_*)&qp[c * Dd + 32 + g * 8];

  auto stageK = [&](int buf, int kb) {
#pragma unroll
    for (int i = 0; i < 2; ++i) {
      int rr = w * 16 + i * 8 + srow;
      int sc = (x8 ^ (rr & 7)) * 8;
      gload_lds16(kbh + (size_t)(kb + rr) * Dd + sc, &Kt[buf][w * 16 + i * 8][0]);
    }
  };
  auto stageV = [&](int buf, int kb) {
#pragma unroll
    for (int i = 0; i < 2; ++i) {
      int rr = w * 16 + i * 8 + srow;
      int sc = (x8 ^ (rr & 7)) * 8;
      gload_lds16(vbh + (size_t)rr * Ls + kb + sc, &Vt[buf][w * 16 + i * 8][0]);
    }
  };

  float4_ accO[4];
#pragma unroll
  for (int dt = 0; dt < 4; ++dt) accO[dt] = z4;
  float rsum4[4] = {0.f, 0.f, 0.f, 0.f};

  stageK(0, 0); stageV(0, 0);
  for (int i = threadIdx.x; i < Ls; i += 256) comb[i] = comb_g[b * Ls + i] * 0.125f;
  __syncthreads();

  int buf = 0;
  // ---------------- pass 1 ----------------
  for (int t = 0; t < 32; ++t) {
    if (t < 31) { stageK(buf ^ 1, (t + 1) * 64); stageV(buf ^ 1, (t + 1) * 64); }
    const int kb = t * 64;
#pragma unroll
    for (int s = 0; s < 4; ++s) {
      int rowK = s * 16 + c;
      short8_ bk0 = *(const short8_*)&Kt[buf][rowK][((g    ) ^ (c & 7)) * 8];
      short8_ bk1 = *(const short8_*)&Kt[buf][rowK][((4 + g) ^ (c & 7)) * 8];
      float4_ st = mfma16(aq0, bk0, z4);
      st = mfma16(aq1, bk1, st);
      float cc = comb[kb + rowK];
#pragma unroll
      for (int r = 0; r < 4; ++r) {
        float e = __expf(st[r] * cc);
        rsum4[r] += e;
        e_w[w][g * 4 + r][s * 16 + c] = f2bf(e);
      }
    }
#pragma unroll
    for (int hf = 0; hf < 2; ++hf) {
      short8_ ea = *(const short8_*)&e_w[w][c][hf * 32 + g * 8];
#pragma unroll
      for (int dt = 0; dt < 4; ++dt) {
        short8_ bv = *(const short8_*)&Vt[buf][dt * 16 + c][((hf * 4 + g) ^ (c & 7)) * 8];
        accO[dt] = mfma16(ea, bv, accO[dt]);
      }
    }
    __syncthreads();
    buf ^= 1;
  }

  // rowsums: reduce across the 16 c-lanes (each wave owns its rows fully)
#pragma unroll
  for (int m = 1; m < 16; m <<= 1)
#pragma unroll
    for (int r = 0; r < 4; ++r) rsum4[r] += __shfl_xor(rsum4[r], m);
  float invr[4];
#pragma unroll
  for (int r = 0; r < 4; ++r) invr[r] = 1.0f / rsum4[r];
  if (c == 0)
#pragma unroll
    for (int r = 0; r < 4; ++r) inv_w[w][g * 4 + r] = invr[r];

  // ctx: normalize, stage in (dead) Vt region, coalesced bf16 dump
  u16* out_lds = &Vt[0][0][0] + w * 1152;   // 16 rows x 72 per wave
#pragma unroll
  for (int dt = 0; dt < 4; ++dt)
#pragma unroll
    for (int r = 0; r < 4; ++r)
      out_lds[(g * 4 + r) * 72 + dt * 16 + c] = f2bf(accO[dt][r] * invr[r]);
  {
    int rr2 = ln >> 2, sg = ln & 3;
    short8_ d0 = *(const short8_*)&out_lds[rr2 * 72 + sg * 16];
    short8_ d1 = *(const short8_*)&out_lds[rr2 * 72 + sg * 16 + 8];
    u16* cp = ctx + ((size_t)(b * Ls + l0 + w * 16 + rr2)) * HD + h * Dd + sg * 16;
    *(short8_*)cp = d0;
    *(short8_*)(cp + 8) = d1;
  }

  // ---------------- pass 2: recompute S^T, write normalized weights ----------------
  float ivq = inv_w[w][c];
  stageK(0, 0);
  __syncthreads();
  buf = 0;
  float* wb = wout + ((size_t)bh * Ls + l0 + w * 16) * Ls;
  for (int t = 0; t < 32; ++t) {
    if (t < 31) stageK(buf ^ 1, (t + 1) * 64);
    const int kb = t * 64;
#pragma unroll
    for (int s = 0; s < 4; ++s) {
      int rowK = s * 16 + c;
      short8_ bk0 = *(const short8_*)&Kt[buf][rowK][((g    ) ^ (c & 7)) * 8];
      short8_ bk1 = *(const short8_*)&Kt[buf][rowK][((4 + g) ^ (c & 7)) * 8];
      // S^T: lane holds keys kb+s*16+g*4+r for q-row c  (operand swap)
      float4_ st = mfma16(bk0, aq0, z4);
      st = mfma16(bk1, aq1, st);
      float4_ cc4 = *(const float4_*)&comb[kb + s * 16 + g * 4];
      float4_ o;
#pragma unroll
      for (int r = 0; r < 4; ++r) o[r] = __expf(st[r] * cc4[r]) * ivq;
      *(float4_*)&wb[(size_t)c * Ls + kb + s * 16 + g * 4] = o;
    }
    __syncthreads();
    buf ^= 1;
  }
}

// ---------------- launch ----------------
extern "C" void kernel_launch(void* const* d_in, const int* in_sizes, int n_in,
                              void* d_out, int out_size, void* d_ws, size_t ws_size,
                              hipStream_t stream) {
  (void)in_sizes; (void)n_in; (void)out_size; (void)ws_size;
  const float* query = (const float*)d_in[0];
  const float* keys  = (const float*)d_in[1];
  const float* values= (const float*)d_in[2];
  const float* focus = (const float*)d_in[3];
  const float* twg   = (const float*)d_in[4];
  const float* iwg   = (const float*)d_in[5];
  const float* Wq = (const float*)d_in[6];  const float* bq = (const float*)d_in[7];
  const float* Wk = (const float*)d_in[8];  const float* bk = (const float*)d_in[9];
  const float* Wv = (const float*)d_in[10]; const float* bv = (const float*)d_in[11];
  const float* Wp = (const float*)d_in[12]; const float* bp = (const float*)d_in[13];
  const float* Wt = (const float*)d_in[14]; const float* bt = (const float*)d_in[15];
  const float* Wi = (const float*)d_in[16]; const float* bi = (const float*)d_in[17];

  char* ws = (char*)d_ws;
  size_t off = 0;
  auto alloc = [&](size_t bytes) -> char* {
    char* p = ws + off; off += (bytes + 255) & ~(size_t)255; return p;
  };
  const size_t NTOK = (size_t)BL * DIMc;          // 4,194,304
  u16* qx   = (u16*)alloc(NTOK * 2);
  u16* kx   = (u16*)alloc(NTOK * 2);
  u16* vx   = (u16*)alloc(NTOK * 2);
  u16* WqT  = (u16*)alloc((size_t)DIMc * HD * 2);
  u16* WkT  = (u16*)alloc((size_t)DIMc * HD * 2);
  u16* WvT  = (u16*)alloc((size_t)DIMc * HD * 2);
  u16* WpT  = (u16*)alloc((size_t)DIMc * HD * 2);
  u16* q_bh = (u16*)alloc(NTOK * 2);
  u16* k_bh = (u16*)alloc(NTOK * 2);
  u16* vTb  = (u16*)alloc(NTOK * 2);
  u16* ctx  = (u16*)alloc(NTOK * 2);
  float* ts   = (float*)alloc((size_t)BL * 4);
  float* is_  = (float*)alloc((size_t)BL * 4);
  float* rs   = (float*)alloc((size_t)BL * 4);
  float* comb = (float*)alloc((size_t)BL * 4);

  float* out_f = (float*)d_out;
  float* w_out = out_f + (size_t)BL * HD;   // weights region

  const int n4 = (int)(NTOK / 4);
  k_cast<<<4096, 256, 0, stream>>>(query,  qx, n4);
  k_cast<<<4096, 256, 0, stream>>>(keys,   kx, n4);
  k_cast<<<4096, 256, 0, stream>>>(values, vx, n4);
  dim3 tg(16, 16);
  k_trans<<<tg, 256, 0, stream>>>(Wq, WqT);
  k_trans<<<tg, 256, 0, stream>>>(Wk, WkT);
  k_trans<<<tg, 256, 0, stream>>>(Wv, WvT);
  k_trans<<<tg, 256, 0, stream>>>(Wp, WpT);
  k_gates<<<1024, 256, 0, stream>>>(keys, Wt, bt, Wi, bi, focus, ts, is_, rs);
  k_combined<<<2, 256, 0, stream>>>(ts, is_, rs, twg, iwg, comb);
  dim3 gg(32, 8);
  k_gemm<0><<<gg, 256, 0, stream>>>(qx, WqT, bq, q_bh);
  k_gemm<0><<<gg, 256, 0, stream>>>(kx, WkT, bk, k_bh);
  k_gemm<2><<<gg, 256, 0, stream>>>(vx, WvT, bv, vTb);
  k_attn2<<<1024, 256, 0, stream>>>(q_bh, k_bh, vTb, comb, w_out, ctx);
  k_gemm<3><<<gg, 256, 0, stream>>>(ctx, WpT, bp, out_f);
}

// Round 3
// 297.558 us; speedup vs baseline: 1.7653x; 1.1475x over previous
//
#include <hip/hip_runtime.h>
#include <hip/hip_bf16.h>
#include <cstdint>

#define DEV static __device__ __forceinline__

typedef __attribute__((ext_vector_type(8))) short short8_;
typedef __attribute__((ext_vector_type(4))) float float4_;
typedef __attribute__((ext_vector_type(4))) float f4v;
typedef __attribute__((ext_vector_type(4))) unsigned short u16x4;
typedef unsigned short u16;

constexpr int Bb   = 2;
constexpr int Ls   = 2048;
constexpr int DIMc = 1024;
constexpr int Hh   = 16;
constexpr int Dd   = 64;
constexpr int BL   = Bb * Ls;   // 4096
constexpr int HD   = Hh * Dd;   // 1024

DEV u16 f2bf(float f) {
  union { float f; uint32_t u; } v; v.f = f;
  return (u16)((v.u + 0x7fffu + ((v.u >> 16) & 1u)) >> 16);
}

DEV float4_ mfma16(short8_ a, short8_ b, float4_ c) {
  return __builtin_amdgcn_mfma_f32_16x16x32_bf16(a, b, c, 0, 0, 0);
}

DEV void gload_lds16(const void* g, void* l) {
  __builtin_amdgcn_global_load_lds(
      (const __attribute__((address_space(1))) void*)g,
      (__attribute__((address_space(3))) void*)l, 16, 0, 0);
}

// ---------------- fused cast fp32 -> bf16 (q,k,v in one launch) ----------------
__global__ void k_cast3(const float* __restrict__ a, const float* __restrict__ b,
                        const float* __restrict__ c, u16* __restrict__ oa,
                        u16* __restrict__ ob, u16* __restrict__ oc) {
  int z = blockIdx.y;
  const float* s = (z == 0) ? a : (z == 1) ? b : c;
  u16* d = (z == 0) ? oa : (z == 1) ? ob : oc;
  int i = blockIdx.x * 256 + threadIdx.x;
  f4v v = ((const f4v*)s)[i];
  u16x4 o = { f2bf(v[0]), f2bf(v[1]), f2bf(v[2]), f2bf(v[3]) };
  ((u16x4*)d)[i] = o;
}

// ---------------- fused transpose + cast W [K][N] -> WT bf16 [N][K] ----------------
__global__ void k_trans4(const float* __restrict__ W0, const float* __restrict__ W1,
                         const float* __restrict__ W2, const float* __restrict__ W3,
                         u16* __restrict__ T0, u16* __restrict__ T1,
                         u16* __restrict__ T2, u16* __restrict__ T3) {
  __shared__ float t[64][65];
  int z = blockIdx.z;
  const float* W = (z == 0) ? W0 : (z == 1) ? W1 : (z == 2) ? W2 : W3;
  u16* WT = (z == 0) ? T0 : (z == 1) ? T1 : (z == 2) ? T2 : T3;
  int tx = threadIdx.x & 63;
  int tg = threadIdx.x >> 6;
  int n0 = blockIdx.x * 64;
  int k0 = blockIdx.y * 64;
#pragma unroll
  for (int i = 0; i < 16; ++i) {
    int r = tg * 16 + i;
    t[r][tx] = W[(size_t)(k0 + r) * HD + n0 + tx];
  }
  __syncthreads();
#pragma unroll
  for (int i = 0; i < 16; ++i) {
    int r = tg * 16 + i;
    WT[(size_t)(n0 + r) * DIMc + k0 + tx] = f2bf(t[tx][r]);
  }
}

// ---------------- gate score dot products (fp32) ----------------
__global__ void k_gates(const float* __restrict__ keys, const float* __restrict__ Wt,
                        const float* __restrict__ bt, const float* __restrict__ Wi,
                        const float* __restrict__ bi, const float* __restrict__ focus,
                        float* __restrict__ ts, float* __restrict__ is_, float* __restrict__ rs) {
  int wv = threadIdx.x >> 6, ln = threadIdx.x & 63;
  int row = blockIdx.x * 4 + wv;          // 0..4095
  int b = row >> 11;
  const float* kr = keys + (size_t)row * DIMc;
  const float* fr = focus + (size_t)b * DIMc;
  float st = 0.f, si = 0.f, sr = 0.f;
  for (int j = ln; j < DIMc; j += 64) {
    float kv = kr[j];
    st += kv * Wt[j]; si += kv * Wi[j]; sr += kv * fr[j];
  }
#pragma unroll
  for (int m = 1; m < 64; m <<= 1) {
    st += __shfl_xor(st, m); si += __shfl_xor(si, m); sr += __shfl_xor(sr, m);
  }
  if (ln == 0) { ts[row] = st + bt[0]; is_[row] = si + bi[0]; rs[row] = sr; }
}

// ------- gate softmaxes + combined (pre-scaled by 1/8 for QK) -------
__global__ void k_combined(const float* __restrict__ ts, const float* __restrict__ is_,
                           const float* __restrict__ rs, const float* __restrict__ tw,
                           const float* __restrict__ iw, float* __restrict__ comb) {
  int b = blockIdx.x, t = threadIdx.x;
  __shared__ float red[3][4];
  float lt[8], li[8], lr[8];
  float m3[3] = {-1e30f, -1e30f, -1e30f};
#pragma unroll
  for (int i = 0; i < 8; ++i) {
    int gi = b * Ls + i * 256 + t;
    lt[i] = ts[gi] * tw[gi];
    li[i] = is_[gi] * iw[gi];
    lr[i] = rs[gi];
    m3[0] = fmaxf(m3[0], lt[i]); m3[1] = fmaxf(m3[1], li[i]); m3[2] = fmaxf(m3[2], lr[i]);
  }
#pragma unroll
  for (int q = 0; q < 3; ++q) {
    float v = m3[q];
#pragma unroll
    for (int m = 32; m; m >>= 1) v = fmaxf(v, __shfl_xor(v, m));
    if ((t & 63) == 0) red[q][t >> 6] = v;
  }
  __syncthreads();
#pragma unroll
  for (int q = 0; q < 3; ++q)
    m3[q] = fmaxf(fmaxf(red[q][0], red[q][1]), fmaxf(red[q][2], red[q][3]));
  __syncthreads();
  float s3[3] = {0.f, 0.f, 0.f};
#pragma unroll
  for (int i = 0; i < 8; ++i) {
    lt[i] = __expf(lt[i] - m3[0]); s3[0] += lt[i];
    li[i] = __expf(li[i] - m3[1]); s3[1] += li[i];
    lr[i] = __expf(lr[i] - m3[2]); s3[2] += lr[i];
  }
#pragma unroll
  for (int q = 0; q < 3; ++q) {
    float v = s3[q];
#pragma unroll
    for (int m = 32; m; m >>= 1) v += __shfl_xor(v, m);
    if ((t & 63) == 0) red[q][t >> 6] = v;
  }
  __syncthreads();
#pragma unroll
  for (int q = 0; q < 3; ++q) s3[q] = red[q][0] + red[q][1] + red[q][2] + red[q][3];
  float rt = 1.f / s3[0], ri = 1.f / s3[1], rr = 1.f / s3[2];
  const float scl = (1.f / 3.f) * 0.125f;   // /3 combine, /8 = 1/sqrt(D) QK scale
#pragma unroll
  for (int i = 0; i < 8; ++i) {
    int gi = b * Ls + i * 256 + t;
    comb[gi] = (lt[i] * rt + li[i] * ri + lr[i] * rr) * scl;
  }
}

// -------- fused QKV GEMM: z selects (A, WT, bias, out, layout) --------
// 768 WGs -> ~3/CU co-residency hides barrier drains.
__launch_bounds__(256, 2)
__global__ void k_gemm_qkv(const u16* __restrict__ qx, const u16* __restrict__ kx,
                           const u16* __restrict__ vx, const u16* __restrict__ WqT,
                           const u16* __restrict__ WkT, const u16* __restrict__ WvT,
                           const float* __restrict__ bq, const float* __restrict__ bk,
                           const float* __restrict__ bv, u16* __restrict__ q_bh,
                           u16* __restrict__ k_bh, u16* __restrict__ vT) {
  __shared__ __align__(16) u16 As[128 * 32];
  __shared__ __align__(16) u16 Bs[128 * 32];
  const int z = blockIdx.z;
  const u16* A  = (z == 0) ? qx : (z == 1) ? kx : vx;
  const u16* BT = (z == 0) ? WqT : (z == 1) ? WkT : WvT;
  const float* bias = (z == 0) ? bq : (z == 1) ? bk : bv;
  const int tid = threadIdx.x, wv = tid >> 6, ln = tid & 63;
  const int g = ln >> 4, c = ln & 15;
  const int m0 = blockIdx.x * 128, n0 = blockIdx.y * 128;
  const int wm = wv >> 1, wn = wv & 1;
  const float4_ z4 = {0.f, 0.f, 0.f, 0.f};
  float4_ acc[4][4];
#pragma unroll
  for (int i = 0; i < 4; ++i)
#pragma unroll
    for (int j = 0; j < 4; ++j) acc[i][j] = z4;
  const int lrow = ln >> 2, lcol = (ln & 3) * 8;
  for (int k0 = 0; k0 < 1024; k0 += 32) {
#pragma unroll
    for (int s = 0; s < 2; ++s) {
      int r0 = wv * 32 + s * 16;
      gload_lds16(A  + (size_t)(m0 + r0 + lrow) * 1024 + k0 + lcol, &As[r0 * 32]);
      gload_lds16(BT + (size_t)(n0 + r0 + lrow) * 1024 + k0 + lcol, &Bs[r0 * 32]);
    }
    __syncthreads();
    short8_ af[4], bfr[4];
#pragma unroll
    for (int mt = 0; mt < 4; ++mt)
      af[mt] = *(const short8_*)&As[(wm * 64 + mt * 16 + c) * 32 + g * 8];
#pragma unroll
    for (int nt = 0; nt < 4; ++nt)
      bfr[nt] = *(const short8_*)&Bs[(wn * 64 + nt * 16 + c) * 32 + g * 8];
#pragma unroll
    for (int mt = 0; mt < 4; ++mt)
#pragma unroll
      for (int nt = 0; nt < 4; ++nt)
        acc[mt][nt] = mfma16(af[mt], bfr[nt], acc[mt][nt]);
    __syncthreads();
  }
  if (z < 2) {  // q_bh / k_bh : bf16 [B,H,L,D]
    u16* Q = (z == 0) ? q_bh : k_bh;
#pragma unroll
    for (int mt = 0; mt < 4; ++mt)
#pragma unroll
      for (int nt = 0; nt < 4; ++nt) {
        int n = n0 + wn * 64 + nt * 16 + c;
        float bv_ = bias[n];
        int h = n >> 6, d = n & 63;
#pragma unroll
        for (int r = 0; r < 4; ++r) {
          int m = m0 + wm * 64 + mt * 16 + g * 4 + r;
          int b = m >> 11, l = m & 2047;
          Q[((size_t)((b * Hh + h) * Ls + l)) * Dd + d] = f2bf(acc[mt][nt][r] + bv_);
        }
      }
  } else {      // vT : bf16 [B,H,D,L]
#pragma unroll
    for (int mt = 0; mt < 4; ++mt)
#pragma unroll
      for (int nt = 0; nt < 4; ++nt) {
        int n = n0 + wn * 64 + nt * 16 + c;
        float bv_ = bias[n];
        int h = n >> 6, d = n & 63;
        int mrow = m0 + wm * 64 + mt * 16 + g * 4;
        int b = mrow >> 11, l = mrow & 2047;
        u16x4 o = { f2bf(acc[mt][nt][0] + bv_), f2bf(acc[mt][nt][1] + bv_),
                    f2bf(acc[mt][nt][2] + bv_), f2bf(acc[mt][nt][3] + bv_) };
        *(u16x4*)&vT[((size_t)((b * Hh + h) * Dd + d)) * Ls + l] = o;
      }
  }
}

// -------- output GEMM: 64x128 tiles -> 512 WGs (2/CU) --------
__launch_bounds__(256, 4)
__global__ void k_gemmO(const u16* __restrict__ A, const u16* __restrict__ BT,
                        const float* __restrict__ bias, float* __restrict__ O) {
  __shared__ __align__(16) u16 As[64 * 32];
  __shared__ __align__(16) u16 Bs[128 * 32];
  const int tid = threadIdx.x, wv = tid >> 6, ln = tid & 63;
  const int g = ln >> 4, c = ln & 15;
  const int m0 = blockIdx.x * 64, n0 = blockIdx.y * 128;
  const int wm = wv >> 1, wn = wv & 1;
  const float4_ z4 = {0.f, 0.f, 0.f, 0.f};
  float4_ acc[2][4];
#pragma unroll
  for (int i = 0; i < 2; ++i)
#pragma unroll
    for (int j = 0; j < 4; ++j) acc[i][j] = z4;
  const int lrow = ln >> 2, lcol = (ln & 3) * 8;
  for (int k0 = 0; k0 < 1024; k0 += 32) {
    gload_lds16(A + (size_t)(m0 + wv * 16 + lrow) * 1024 + k0 + lcol, &As[(wv * 16) * 32]);
#pragma unroll
    for (int s = 0; s < 2; ++s) {
      int r0 = wv * 32 + s * 16;
      gload_lds16(BT + (size_t)(n0 + r0 + lrow) * 1024 + k0 + lcol, &Bs[r0 * 32]);
    }
    __syncthreads();
    short8_ af[2], bfr[4];
#pragma unroll
    for (int mt = 0; mt < 2; ++mt)
      af[mt] = *(const short8_*)&As[(wm * 32 + mt * 16 + c) * 32 + g * 8];
#pragma unroll
    for (int nt = 0; nt < 4; ++nt)
      bfr[nt] = *(const short8_*)&Bs[(wn * 64 + nt * 16 + c) * 32 + g * 8];
#pragma unroll
    for (int mt = 0; mt < 2; ++mt)
#pragma unroll
      for (int nt = 0; nt < 4; ++nt)
        acc[mt][nt] = mfma16(af[mt], bfr[nt], acc[mt][nt]);
    __syncthreads();
  }
#pragma unroll
  for (int mt = 0; mt < 2; ++mt)
#pragma unroll
    for (int nt = 0; nt < 4; ++nt) {
      int n = n0 + wn * 64 + nt * 16 + c;
      float bv_ = bias[n];
#pragma unroll
      for (int r = 0; r < 4; ++r) {
        int m = m0 + wm * 32 + mt * 16 + g * 4 + r;
        O[(size_t)m * HD + n] = acc[mt][nt][r] + bv_;
      }
    }
}

// ---------------- attention v3: 40KB LDS -> 4 WG/CU, all 1024 WGs resident ----
__launch_bounds__(256, 4)
__global__ void k_attn3(const u16* __restrict__ q_bh, const u16* __restrict__ k_bh,
                        const u16* __restrict__ vT, const float* __restrict__ comb_g,
                        float* __restrict__ wout, u16* __restrict__ ctx) {
  __shared__ __align__(16) u16 Kt[2][64][64];
  __shared__ __align__(16) u16 Vt[2][64][64];   // aliased for ctx staging after pass 1
  __shared__ __align__(16) u16 e_w[4][16][64];  // XOR-swizzled; aliased for inv after pass 1

  const int bid = blockIdx.x;
  const int logical = (bid & 7) * 128 + (bid >> 3);   // bijective: 4 bh per XCD
  const int bh = logical >> 5, qb = logical & 31;
  const int b = bh >> 4, h = bh & 15;
  const int l0 = qb * 64;
  const int w = threadIdx.x >> 6, ln = threadIdx.x & 63;
  const int g = ln >> 4, c = ln & 15;
  const int srow = ln >> 3, x8 = ln & 7;   // staging lane coords
  const float4_ z4 = {0.f, 0.f, 0.f, 0.f};

  const u16* kbh = k_bh + (size_t)bh * Ls * Dd;
  const u16* vbh = vT + (size_t)bh * Dd * Ls;
  const float* kcomb = comb_g + (size_t)b * Ls;   // pre-scaled by 1/8 already

  // per-wave Q fragments (rows l0 + w*16 + c)
  const u16* qp = q_bh + ((size_t)bh * Ls + l0 + w * 16) * Dd;
  short8_ aq0 = *(const short8_*)&qp[c * Dd + g * 8];
  short8_ aq1 = *(const short8_*)&qp[c * Dd + 32 + g * 8];

  auto stageK = [&](int buf, int kb) {
#pragma unroll
    for (int i = 0; i < 2; ++i) {
      int rr = w * 16 + i * 8 + srow;
      int sc = (x8 ^ (rr & 7)) * 8;
      gload_lds16(kbh + (size_t)(kb + rr) * Dd + sc, &Kt[buf][w * 16 + i * 8][0]);
    }
  };
  auto stageV = [&](int buf, int kb) {
#pragma unroll
    for (int i = 0; i < 2; ++i) {
      int rr = w * 16 + i * 8 + srow;
      int sc = (x8 ^ (rr & 7)) * 8;
      gload_lds16(vbh + (size_t)rr * Ls + kb + sc, &Vt[buf][w * 16 + i * 8][0]);
    }
  };

  float4_ accO[4];
#pragma unroll
  for (int dt = 0; dt < 4; ++dt) accO[dt] = z4;
  float rsum4[4] = {0.f, 0.f, 0.f, 0.f};

  stageK(0, 0); stageV(0, 0);
  __syncthreads();

  int buf = 0;
  // ---------------- pass 1 ----------------
  for (int t = 0; t < 32; ++t) {
    if (t < 31) { stageK(buf ^ 1, (t + 1) * 64); stageV(buf ^ 1, (t + 1) * 64); }
    const int kb = t * 64;
#pragma unroll
    for (int s = 0; s < 4; ++s) {
      int rowK = s * 16 + c;
      short8_ bk0 = *(const short8_*)&Kt[buf][rowK][((g    ) ^ (c & 7)) * 8];
      short8_ bk1 = *(const short8_*)&Kt[buf][rowK][((4 + g) ^ (c & 7)) * 8];
      float4_ st = mfma16(aq0, bk0, z4);
      st = mfma16(aq1, bk1, st);
      float cc = kcomb[kb + rowK];
      int chunk0 = s * 2 + (c >> 3), w7 = c & 7;
#pragma unroll
      for (int r = 0; r < 4; ++r) {
        float e = __expf(st[r] * cc);
        rsum4[r] += e;
        int row = g * 4 + r;
        e_w[w][row][((chunk0 ^ (row & 7)) << 3) | w7] = f2bf(e);
      }
    }
#pragma unroll
    for (int hf = 0; hf < 2; ++hf) {
      short8_ ea = *(const short8_*)&e_w[w][c][(((hf * 4 + g) ^ (c & 7)) << 3)];
#pragma unroll
      for (int dt = 0; dt < 4; ++dt) {
        short8_ bv = *(const short8_*)&Vt[buf][dt * 16 + c][((hf * 4 + g) ^ (c & 7)) * 8];
        accO[dt] = mfma16(ea, bv, accO[dt]);
      }
    }
    __syncthreads();
    buf ^= 1;
  }

  // rowsums: reduce across the 16 c-lanes (each wave owns its rows fully)
#pragma unroll
  for (int m = 1; m < 16; m <<= 1)
#pragma unroll
    for (int r = 0; r < 4; ++r) rsum4[r] += __shfl_xor(rsum4[r], m);
  float invr[4];
#pragma unroll
  for (int r = 0; r < 4; ++r) invr[r] = 1.0f / rsum4[r];
  // inv per q-row, staged in dead e_w (wave-private -> no barrier needed)
  float* ivp = (float*)&e_w[w][0][0];
  if (c == 0)
#pragma unroll
    for (int r = 0; r < 4; ++r) ivp[g * 4 + r] = invr[r];

  // ctx: normalize, stage in (dead) Vt region, coalesced bf16 dump
  u16* out_lds = &Vt[0][0][0] + w * 1152;   // 16 rows x 72 per wave
#pragma unroll
  for (int dt = 0; dt < 4; ++dt)
#pragma unroll
    for (int r = 0; r < 4; ++r)
      out_lds[(g * 4 + r) * 72 + dt * 16 + c] = f2bf(accO[dt][r] * invr[r]);
  {
    int rr2 = ln >> 2, sg = ln & 3;
    short8_ d0 = *(const short8_*)&out_lds[rr2 * 72 + sg * 16];
    short8_ d1 = *(const short8_*)&out_lds[rr2 * 72 + sg * 16 + 8];
    u16* cp = ctx + ((size_t)(b * Ls + l0 + w * 16 + rr2)) * HD + h * Dd + sg * 16;
    *(short8_*)cp = d0;
    *(short8_*)(cp + 8) = d1;
  }

  // ---------------- pass 2: recompute S^T, write normalized weights ----------------
  float ivq = ivp[c];
  stageK(0, 0);
  __syncthreads();
  buf = 0;
  float* wb = wout + ((size_t)bh * Ls + l0 + w * 16) * Ls;
  for (int t = 0; t < 32; ++t) {
    if (t < 31) stageK(buf ^ 1, (t + 1) * 64);
    const int kb = t * 64;
#pragma unroll
    for (int s = 0; s < 4; ++s) {
      int rowK = s * 16 + c;
      short8_ bk0 = *(const short8_*)&Kt[buf][rowK][((g    ) ^ (c & 7)) * 8];
      short8_ bk1 = *(const short8_*)&Kt[buf][rowK][((4 + g) ^ (c & 7)) * 8];
      // S^T: lane holds keys kb+s*16+g*4+r for q-row c  (operand swap)
      float4_ st = mfma16(bk0, aq0, z4);
      st = mfma16(bk1, aq1, st);
      float4_ cc4 = *(const float4_*)&kcomb[kb + s * 16 + g * 4];
      float4_ o;
#pragma unroll
      for (int r = 0; r < 4; ++r) o[r] = __expf(st[r] * cc4[r]) * ivq;
      *(float4_*)&wb[(size_t)c * Ls + kb + s * 16 + g * 4] = o;
    }
    __syncthreads();
    buf ^= 1;
  }
}

// ---------------- launch ----------------
extern "C" void kernel_launch(void* const* d_in, const int* in_sizes, int n_in,
                              void* d_out, int out_size, void* d_ws, size_t ws_size,
                              hipStream_t stream) {
  (void)in_sizes; (void)n_in; (void)out_size; (void)ws_size;
  const float* query = (const float*)d_in[0];
  const float* keys  = (const float*)d_in[1];
  const float* values= (const float*)d_in[2];
  const float* focus = (const float*)d_in[3];
  const float* twg   = (const float*)d_in[4];
  const float* iwg   = (const float*)d_in[5];
  const float* Wq = (const float*)d_in[6];  const float* bq = (const float*)d_in[7];
  const float* Wk = (const float*)d_in[8];  const float* bk = (const float*)d_in[9];
  const float* Wv = (const float*)d_in[10]; const float* bv = (const float*)d_in[11];
  const float* Wp = (const float*)d_in[12]; const float* bp = (const float*)d_in[13];
  const float* Wt = (const float*)d_in[14]; const float* bt = (const float*)d_in[15];
  const float* Wi = (const float*)d_in[16]; const float* bi = (const float*)d_in[17];

  char* ws = (char*)d_ws;
  size_t off = 0;
  auto alloc = [&](size_t bytes) -> char* {
    char* p = ws + off; off += (bytes + 255) & ~(size_t)255; return p;
  };
  const size_t NTOK = (size_t)BL * DIMc;          // 4,194,304
  u16* qx   = (u16*)alloc(NTOK * 2);
  u16* kx   = (u16*)alloc(NTOK * 2);
  u16* vx   = (u16*)alloc(NTOK * 2);
  u16* WqT  = (u16*)alloc((size_t)DIMc * HD * 2);
  u16* WkT  = (u16*)alloc((size_t)DIMc * HD * 2);
  u16* WvT  = (u16*)alloc((size_t)DIMc * HD * 2);
  u16* WpT  = (u16*)alloc((size_t)DIMc * HD * 2);
  u16* q_bh = (u16*)alloc(NTOK * 2);
  u16* k_bh = (u16*)alloc(NTOK * 2);
  u16* vTb  = (u16*)alloc(NTOK * 2);
  u16* ctx  = (u16*)alloc(NTOK * 2);
  float* ts   = (float*)alloc((size_t)BL * 4);
  float* is_  = (float*)alloc((size_t)BL * 4);
  float* rs   = (float*)alloc((size_t)BL * 4);
  float* comb = (float*)alloc((size_t)BL * 4);

  float* out_f = (float*)d_out;
  float* w_out = out_f + (size_t)BL * HD;   // weights region

  dim3 cg(4096, 3);
  k_cast3<<<cg, 256, 0, stream>>>(query, keys, values, qx, kx, vx);
  dim3 tg(16, 16, 4);
  k_trans4<<<tg, 256, 0, stream>>>(Wq, Wk, Wv, Wp, WqT, WkT, WvT, WpT);
  k_gates<<<1024, 256, 0, stream>>>(keys, Wt, bt, Wi, bi, focus, ts, is_, rs);
  k_combined<<<2, 256, 0, stream>>>(ts, is_, rs, twg, iwg, comb);
  dim3 gq(32, 8, 3);
  k_gemm_qkv<<<gq, 256, 0, stream>>>(qx, kx, vx, WqT, WkT, WvT, bq, bk, bv,
                                     q_bh, k_bh, vTb);
  k_attn3<<<1024, 256, 0, stream>>>(q_bh, k_bh, vTb, comb, w_out, ctx);
  dim3 go(64, 8);
  k_gemmO<<<go, 256, 0, stream>>>(ctx, WpT, bp, out_f);
}